// Round 16
// baseline (1331.125 us; speedup 1.0000x reference)
//
#include <hip/hip_runtime.h>
#include <math.h>

typedef unsigned int uint;
typedef unsigned long long ull;
typedef unsigned short ushort;

#define DM   512
#define DS   128
#define TT   20
#define NL   4
#define NV   32000
#define NROW 2048

// ws layout (~10.4 MB)
#define OFF_A2  0u          // 4*128*64 float2  A2[l][j][i2] = (A[i2][j], A[i2+64][j])
#define OFF_B2  262144u     // 4*512*64 float2  B2[l][d][i2] = (B[i2][d], B[i2+64][d])
#define OFF_X0  2359296u    // 2048*20*16 u32   spike masks ping (bit d&31 of word d>>5)
#define OFF_X1  4980736u    // 2621440          spike masks pong
#define OFF_H   7602176u    // 2048*20*4 u32    h masks
#define OFF_TIB 8257536u    // 2048*512 bf16    time-integrated

// d_out scratch (gemm fully overwrites d_out last):
//   su: [row][t][lane] float2 = 20,971,520 B at offset 0
//   C4: [l][j][dgw][lane] float4 = 2,097,152 B at offset 32 MB
#define C4_OFF_OUT 33554432u

typedef float f32x2 __attribute__((ext_vector_type(2)));
typedef float f32x4 __attribute__((ext_vector_type(4)));
typedef __bf16 bf16x8 __attribute__((ext_vector_type(8)));
typedef ushort us8 __attribute__((ext_vector_type(8)));

__device__ __forceinline__ ushort f2bf(float f){   // RNE f32->bf16
  uint x = __float_as_uint(f);
  uint r = x + 0x7fffu + ((x >> 16) & 1u);
  return (ushort)(r >> 16);
}

// ---------------- weight prep: paired A/B layouts + packed C4 ----------------
__global__ __launch_bounds__(256) void bt_transpose_k(
    const float* __restrict__ A, const float* __restrict__ B, const float* __restrict__ C,
    float2* __restrict__ A2, float2* __restrict__ B2, float4* __restrict__ C4){
  int tid = blockIdx.x * 256 + threadIdx.x;
  int nth = gridDim.x * 256;
  for (int idx = tid; idx < 4*128*64; idx += nth){
    int l = idx >> 13, j = (idx >> 6) & 127, i = idx & 63;
    A2[idx] = make_float2(A[l*16384 + i*128 + j], A[l*16384 + (i+64)*128 + j]);
  }
  for (int idx = tid; idx < 4*512*64; idx += nth){
    int l = idx >> 15, d = (idx >> 6) & 511, i = idx & 63;
    B2[idx] = make_float2(B[l*65536 + i*512 + d], B[l*65536 + (i+64)*512 + d]);
  }
  // C4[((l*128 + j)*2 + dgw)*64 + i] = C[l][dgw*256 + k*64 + i][j] for k=0..3
  for (int idx = tid; idx < 4*128*2*64; idx += nth){
    int l = idx >> 14, rem = idx & 16383;
    int j = rem >> 7, dgw = (rem >> 6) & 1, i = rem & 63;
    const float* Cl = C + l*65536;
    C4[idx] = make_float4(Cl[(dgw*256 +   0 + i)*128 + j],
                          Cl[(dgw*256 +  64 + i)*128 + j],
                          Cl[(dgw*256 + 128 + i)*128 + j],
                          Cl[(dgw*256 + 192 + i)*128 + j]);
  }
}

// ---------------- temporal encode -> bitmasks (verified) ----------------
__global__ __launch_bounds__(256) void enc_k(
    const int* __restrict__ ids, const float* __restrict__ emb, uint* __restrict__ X0){
  int tid = threadIdx.x;
  int h = tid & 31, rloc = tid >> 5;
  int r = blockIdx.x * 8 + rloc;
  int id = ids[r];
  uint half = (uint)((rloc & 1) * 32);
  int kk[16];
  #pragma unroll
  for (int w = 0; w < 16; w++){
    float e    = emb[(size_t)id * DM + w*32 + h];
    float ex32 = (float)exp(-(double)e);     // correctly-rounded f32 exp(-x)
    float sg   = 1.0f / (1.0f + ex32);
    float p    = sg * 19.0f;
    int k = (int)floorf(p);
    if (k > TT-1) k = TT-1;
    kk[w] = k;
  }
  uint* Xr = X0 + (size_t)r * (TT*16);
  for (int t = 0; t < TT; t++){
    #pragma unroll
    for (int w = 0; w < 16; w++){
      uint bw = (uint)(__ballot(kk[w] == t) >> half);
      if (h == 0) Xr[t*16 + w] = bw;
    }
  }
}

// ---------------- A1: su_pre = x @ B.T, 10 t per wave, PIPELINED LDS B ----------------
// 1024 blocks x 256 thr = 4 waves = 2 rows x 2 t-halves; 4 blocks/CU (32 KB LDS).
// 16 chunks x 32 d (16 KB, one mask word each), DOUBLE-buffered: at iter c we
// ISSUE gload_lds for chunk c+1 + prefetch its masks, THEN consume chunk c
// (~700 cyc of ds_read+fma hides the loads), THEN barrier (vmcnt confirm).
// r15's bug was stage->barrier->consume (latency fully exposed).
// Chain per (t,i): single f32 acc, d ascending (chunk, bit) -> bit-exact.
__global__ __launch_bounds__(256) void snn_a1_k(
    int l, const uint* __restrict__ Xin, const float2* __restrict__ B2,
    float2* __restrict__ su){
  __shared__ float2 Bs[2][32*64];     // 2 x 16 KB
  int tid = threadIdx.x;
  int lane = tid & 63, wv = tid >> 6;
  size_t r = (size_t)blockIdx.x * 2 + (wv >> 1);
  int th = wv & 1;
  const uint* Xr = Xin + r * (TT*16) + th*10*16;

  float acc0[10], acc1[10];
  #pragma unroll
  for (int t = 0; t < 10; t++){ acc0[t] = 0.0f; acc1[t] = 0.0f; }

  const char* Bbase = (const char*)(B2 + (size_t)l * 32768);
  // prologue: stage chunk 0 -> buf 0; load chunk-0 masks
  #pragma unroll
  for (int i = 0; i < 4; i++){
    int slot = tid + i*256;
    __builtin_amdgcn_global_load_lds(
        (const __attribute__((address_space(1))) void*)(Bbase + (size_t)slot*16),
        (__attribute__((address_space(3))) void*)((char*)&Bs[0][0] + slot*16), 16, 0, 0);
  }
  uint swv[10];
  #pragma unroll
  for (int t = 0; t < 10; t++) swv[t] = Xr[t*16];
  __syncthreads();                           // chunk 0 landed

  for (int c = 0; c < 16; c++){
    int cur = c & 1;
    if (c < 15){                             // ISSUE next chunk early (idle buffer)
      const char* src = Bbase + (size_t)(c + 1) * 16384;
      #pragma unroll
      for (int i = 0; i < 4; i++){
        int slot = tid + i*256;
        __builtin_amdgcn_global_load_lds(
            (const __attribute__((address_space(1))) void*)(src + (size_t)slot*16),
            (__attribute__((address_space(3))) void*)((char*)&Bs[cur^1][0] + slot*16), 16, 0, 0);
      }
    }
    uint sw[10];                             // current-chunk masks -> SGPR
    #pragma unroll
    for (int t = 0; t < 10; t++) sw[t] = __builtin_amdgcn_readfirstlane(swv[t]);
    if (c < 15){                             // prefetch next-chunk masks (latency hidden)
      #pragma unroll
      for (int t = 0; t < 10; t++) swv[t] = Xr[t*16 + (c + 1)];
    }
    // consume chunk c: d ascending
    #pragma unroll 8
    for (int db = 0; db < 32; db++){
      float2 b = Bs[cur][db*64 + lane];
      #pragma unroll
      for (int t = 0; t < 10; t++){
        float sf = ((sw[t] >> db) & 1u) ? 1.0f : 0.0f;   // wave-uniform (SALU)
        acc0[t] = fmaf(sf, b.x, acc0[t]);
        acc1[t] = fmaf(sf, b.y, acc1[t]);
      }
    }
    __syncthreads();                         // next chunk landed + cur free for re-stage
  }
  float2* sp = su + (r*20 + th*10)*64 + lane;
  #pragma unroll
  for (int t = 0; t < 10; t++)
    sp[t*64] = make_float2(acc0[t], acc1[t]);
}

// ---------------- A2: LIF1 recurrence over t -> H masks (r14-verbatim) ----------------
__global__ __launch_bounds__(256) void snn_a2_k(
    int l, const float2* __restrict__ su, const float2* __restrict__ A2w,
    uint* __restrict__ H){
  __shared__ float2 As[128*64];    // As[j*64+i2] = (A[i2][j], A[i2+64][j])
  int tid = threadIdx.x;
  int lane = tid & 63, wv = tid >> 6;
  size_t r = (size_t)blockIdx.x * 4 + wv;

  { const float4* Ag = (const float4*)(A2w + l * 8192);
    float4* Asv = (float4*)As;
    #pragma unroll
    for (int p = 0; p < 16; p++) Asv[tid + p*256] = Ag[tid + p*256]; }
  __syncthreads();

  f32x2 sut[20];
  { const float2* sp = su + r*20*64 + lane;
    #pragma unroll
    for (int t = 0; t < TT; t++){ float2 v = sp[t*64]; sut[t] = (f32x2){v.x, v.y}; } }

  f32x2 v1 = {0.f, 0.f};
  ull m0 = 0, m1 = 0;
  #pragma unroll
  for (int t = 0; t < TT; t++){
    f32x2 t1 = {0.f, 0.f};
    #pragma unroll 8
    for (int j = 0; j < 64; j++){
      float sf = ((m0 >> j) & 1ull) ? 1.0f : 0.0f;
      float2 a = As[j*64 + lane];
      t1 = __builtin_elementwise_fma((f32x2){sf, sf}, (f32x2){a.x, a.y}, t1);
    }
    #pragma unroll 8
    for (int j = 0; j < 64; j++){
      float sf = ((m1 >> j) & 1ull) ? 1.0f : 0.0f;
      float2 a = As[(64 + j)*64 + lane];
      t1 = __builtin_elementwise_fma((f32x2){sf, sf}, (f32x2){a.x, a.y}, t1);
    }
    f32x2 s_ = t1 + sut[t];               // np: (h@A.T) + (x@B.T), one add per half
    v1 = v1 + (s_ - v1) * 0.5f;           // LIF, tau=2 (exact *0.5)
    bool sa = (v1.x >= 1.0f), sb = (v1.y >= 1.0f);
    if (sa) v1.x = 0.0f;                  // hard reset
    if (sb) v1.y = 0.0f;
    m0 = __ballot(sa);
    m1 = __ballot(sb);
    if (lane == 0)
      *(uint4*)(H + (r*TT + t)*4) =
        make_uint4((uint)m0, (uint)(m0 >> 32), (uint)m1, (uint)(m1 >> 32));
  }
}

// ---------------- kernel B: H@C.T then LIF2 -> X' (C4 packed loads) ----------------
__global__ __launch_bounds__(256, 4) void snn_b_k(
    int l, int last, const uint* __restrict__ Xin, const uint* __restrict__ Hg,
    const float4* __restrict__ C4, const float* __restrict__ Dfull,
    uint* __restrict__ Xout, ushort* __restrict__ tib){
  int tid = threadIdx.x;
  int lane = tid & 63, wv = tid >> 6;
  int rloc = wv >> 1, dgw = wv & 1;
  size_t r = (size_t)blockIdx.x * 2 + rloc;

  float acc[TT][4];
  #pragma unroll
  for (int t = 0; t < TT; t++){ acc[t][0]=0.f; acc[t][1]=0.f; acc[t][2]=0.f; acc[t][3]=0.f; }

  const float4* Cp = C4 + (((size_t)l*128)*2 + dgw)*64 + lane;   // per j: Cp[j*128]
  const uint*   Hr = Hg + r * (TT*4);
  for (int jw = 0; jw < 4; jw++){
    uint sw[TT];
    #pragma unroll
    for (int t = 0; t < TT; t++)
      sw[t] = __builtin_amdgcn_readfirstlane(Hr[t*4 + jw]);
    #pragma unroll 4
    for (int jb = 0; jb < 32; jb++){
      float4 cv = Cp[(size_t)(jw*32 + jb) * 128];
      float c0 = cv.x, c1 = cv.y, c2 = cv.z, c3 = cv.w;
      #pragma unroll
      for (int t = 0; t < TT; t++){
        float sf = ((sw[t] >> jb) & 1u) ? 1.0f : 0.0f;
        acc[t][0] = fmaf(sf, c0, acc[t][0]);
        acc[t][1] = fmaf(sf, c1, acc[t][1]);
        acc[t][2] = fmaf(sf, c2, acc[t][2]);
        acc[t][3] = fmaf(sf, c3, acc[t][3]);
      }
    }
  }

  // LIF2 over t (fully unrolled)
  float dv[4];
  #pragma unroll
  for (int k = 0; k < 4; k++) dv[k] = Dfull[l*DM + dgw*256 + k*64 + lane];
  float v2[4] = {0.f,0.f,0.f,0.f};
  int cnt[4] = {0,0,0,0};
  const uint* Xr = Xin + r * (TT*16) + dgw*8 + (lane >> 5);
  #pragma unroll
  for (int t = 0; t < TT; t++){
    bool s[4];
    #pragma unroll
    for (int k = 0; k < 4; k++){
      uint xw = Xr[t*16 + k*2];
      float t4 = ((xw >> (lane & 31)) & 1u) ? dv[k] : 0.0f;  // x_t * D
      float ou = acc[t][k] + t4;              // np: (h@C.T) + x*D, one add
      v2[k] = v2[k] + (ou - v2[k]) * 0.5f;
      s[k] = (v2[k] >= 1.0f);
      if (s[k]) v2[k] = 0.0f;
    }
    if (!last){
      #pragma unroll
      for (int k = 0; k < 4; k++){
        ull bm = __ballot(s[k]);
        if (lane == 0){
          Xout[(r*TT + t)*16 + dgw*8 + k*2]     = (uint)bm;
          Xout[(r*TT + t)*16 + dgw*8 + k*2 + 1] = (uint)(bm >> 32);
        }
      }
    } else {
      #pragma unroll
      for (int k = 0; k < 4; k++) cnt[k] += s[k] ? 1 : 0;
    }
  }
  if (last){
    #pragma unroll
    for (int k = 0; k < 4; k++)
      tib[r*DM + dgw*256 + k*64 + lane] = f2bf((float)cnt[k] / 20.0f);
  }
}

// ---------------- final projection: bf16 MFMA, BM=256 tile + XCD panel swizzle ----------------
__global__ __launch_bounds__(512, 2) void gemm_mfma_k(
    const ushort* __restrict__ tib, const float* __restrict__ Wp,
    const float* __restrict__ bp, float* __restrict__ out){
  __shared__ ushort lA[256*64];    // 32 KB
  __shared__ ushort lB[128*64];    // 16 KB
  int bid = blockIdx.x;
  int L = (bid & 7) * 250 + (bid >> 3);    // bijective on [0,2000)
  int m0 = (L & 7) * 256;
  int n0 = (L >> 3) * 128;
  int tid = threadIdx.x;
  int lane = tid & 63, wv = tid >> 6;      // 8 waves
  int wm = wv >> 1, wn = wv & 1;

  f32x4 acc[4][4];
  #pragma unroll
  for (int i = 0; i < 4; i++)
    #pragma unroll
    for (int j = 0; j < 4; j++) acc[i][j] = (f32x4){0.f,0.f,0.f,0.f};

  for (int k0 = 0; k0 < 512; k0 += 64){
    __syncthreads();
    #pragma unroll
    for (int i = 0; i < 4; i++){     // A: 256x64, global_load_lds 16B, pre-swizzled src
      int slot = tid + i*512; int row = slot >> 3; int cb8 = (slot & 7) * 8;
      int sc = cb8 ^ ((row & 7) * 8);
      const ushort* gp = tib + (size_t)(m0 + row) * 512 + k0 + sc;
      __builtin_amdgcn_global_load_lds((const __attribute__((address_space(1))) void*)gp,
          (__attribute__((address_space(3))) void*)&lA[slot*8], 16, 0, 0);
    }
    #pragma unroll
    for (int i = 0; i < 2; i++){     // B: 128x64, reg-stage f32 -> bf16, swizzled dest
      int slot = tid + i*512; int row = slot >> 3; int cb8 = (slot & 7) * 8;
      int sc = cb8 ^ ((row & 7) * 8);
      const float* gp = Wp + (size_t)(n0 + row) * 512 + k0 + sc;
      float4 u = *(const float4*)gp;
      float4 v = *(const float4*)(gp + 4);
      us8 pk;
      pk[0]=f2bf(u.x); pk[1]=f2bf(u.y); pk[2]=f2bf(u.z); pk[3]=f2bf(u.w);
      pk[4]=f2bf(v.x); pk[5]=f2bf(v.y); pk[6]=f2bf(v.z); pk[7]=f2bf(v.w);
      *(us8*)&lB[slot*8] = pk;
    }
    __syncthreads();
    #pragma unroll
    for (int kk = 0; kk < 2; kk++){
      bf16x8 af[4], bf_[4];
      int c = kk*32 + (lane >> 4) * 8;
      #pragma unroll
      for (int mi = 0; mi < 4; mi++){
        int row = wm*64 + mi*16 + (lane & 15);
        af[mi] = *(const bf16x8*)&lA[row*64 + (c ^ ((row & 7) * 8))];
      }
      #pragma unroll
      for (int ni = 0; ni < 4; ni++){
        int row = wn*64 + ni*16 + (lane & 15);
        bf_[ni] = *(const bf16x8*)&lB[row*64 + (c ^ ((row & 7) * 8))];
      }
      #pragma unroll
      for (int mi = 0; mi < 4; mi++)
        #pragma unroll
        for (int ni = 0; ni < 4; ni++)
          acc[mi][ni] = __builtin_amdgcn_mfma_f32_16x16x32_bf16(af[mi], bf_[ni], acc[mi][ni], 0, 0, 0);
    }
  }

  #pragma unroll
  for (int ni = 0; ni < 4; ni++){
    int col = n0 + wn*64 + ni*16 + (lane & 15);
    float bb = bp[col];
    #pragma unroll
    for (int mi = 0; mi < 4; mi++){
      int rbase_ = m0 + wm*64 + mi*16 + (lane >> 4) * 4;
      #pragma unroll
      for (int rr = 0; rr < 4; rr++)
        out[(size_t)(rbase_ + rr) * NV + col] = acc[mi][ni][rr] + bb;
    }
  }
}

extern "C" void kernel_launch(void* const* d_in, const int* in_sizes, int n_in,
                              void* d_out, int out_size, void* d_ws, size_t ws_size,
                              hipStream_t stream) {
  const int*   ids = (const int*)  d_in[0];
  const float* emb = (const float*)d_in[1];
  const float* A   = (const float*)d_in[2];
  const float* B   = (const float*)d_in[3];
  const float* C   = (const float*)d_in[4];
  const float* D   = (const float*)d_in[5];
  const float* Wp  = (const float*)d_in[6];
  const float* bp  = (const float*)d_in[7];
  float* out = (float*)d_out;
  char* ws = (char*)d_ws;
  float2* A2  = (float2*)(ws + OFF_A2);
  float2* B2  = (float2*)(ws + OFF_B2);
  uint*   X0  = (uint*)  (ws + OFF_X0);
  uint*   X1  = (uint*)  (ws + OFF_X1);
  uint*   H   = (uint*)  (ws + OFF_H);
  ushort* tib = (ushort*)(ws + OFF_TIB);
  // d_out scratch (consumed before gemm overwrites)
  float2* su  = (float2*)d_out;
  float4* C4  = (float4*)((char*)d_out + C4_OFF_OUT);

  bt_transpose_k<<<dim3(512), dim3(256), 0, stream>>>(A, B, C, A2, B2, C4);
  enc_k         <<<dim3(256), dim3(256), 0, stream>>>(ids, emb, X0);
  for (int l = 0; l < NL; l++){
    uint* Xin  = (l & 1) ? X1 : X0;
    uint* Xout = (l & 1) ? X0 : X1;
    snn_a1_k<<<dim3(1024), dim3(256), 0, stream>>>(l, Xin, B2, su);
    snn_a2_k<<<dim3(512),  dim3(256), 0, stream>>>(l, su, A2, H);
    snn_b_k <<<dim3(1024), dim3(256), 0, stream>>>(l, (l == NL-1) ? 1 : 0, Xin, H, C4, D, Xout, tib);
  }
  gemm_mfma_k<<<dim3(2000), dim3(512), 0, stream>>>(tib, Wp, bp, out);
}

// Round 17
// 1121.106 us; speedup vs baseline: 1.1873x; 1.1873x over previous
//
#include <hip/hip_runtime.h>
#include <math.h>

typedef unsigned int uint;
typedef unsigned long long ull;
typedef unsigned short ushort;

#define DM   512
#define DS   128
#define TT   20
#define NL   4
#define NV   32000
#define NROW 2048

// packed (1.0f,1.0f) for the wave-uniform pk_fma selector (SGPR pair)
#define ONE2 0x3F8000003F800000ull

// ws layout (~10.4 MB)
#define OFF_A2  0u          // 4*128*64 float2  A2[l][j][i2] = (A[i2][j], A[i2+64][j])
#define OFF_B2  262144u     // 4*512*64 float2  B2[l][d][i2] = (B[i2][d], B[i2+64][d])
#define OFF_X0  2359296u    // 2048*20*16 u32   spike masks ping (bit d&31 of word d>>5)
#define OFF_X1  4980736u    // 2621440          spike masks pong
#define OFF_H   7602176u    // 2048*20*4 u32    h masks
#define OFF_TIB 8257536u    // 2048*512 bf16    time-integrated

// d_out scratch (gemm fully overwrites d_out last):
//   C4: [l][j][dgw][lane] float4 = 2,097,152 B at offset 32 MB
#define C4_OFF_OUT 33554432u

typedef float f32x2 __attribute__((ext_vector_type(2)));
typedef float f32x4 __attribute__((ext_vector_type(4)));
typedef __bf16 bf16x8 __attribute__((ext_vector_type(8)));
typedef ushort us8 __attribute__((ext_vector_type(8)));

__device__ __forceinline__ ushort f2bf(float f){   // RNE f32->bf16
  uint x = __float_as_uint(f);
  uint r = x + 0x7fffu + ((x >> 16) & 1u);
  return (ushort)(r >> 16);
}

// ---------------- weight prep: paired A/B layouts + packed C4 ----------------
__global__ __launch_bounds__(256) void bt_transpose_k(
    const float* __restrict__ A, const float* __restrict__ B, const float* __restrict__ C,
    float2* __restrict__ A2, float2* __restrict__ B2, float4* __restrict__ C4){
  int tid = blockIdx.x * 256 + threadIdx.x;
  int nth = gridDim.x * 256;
  for (int idx = tid; idx < 4*128*64; idx += nth){
    int l = idx >> 13, j = (idx >> 6) & 127, i = idx & 63;
    A2[idx] = make_float2(A[l*16384 + i*128 + j], A[l*16384 + (i+64)*128 + j]);
  }
  for (int idx = tid; idx < 4*512*64; idx += nth){
    int l = idx >> 15, d = (idx >> 6) & 511, i = idx & 63;
    B2[idx] = make_float2(B[l*65536 + i*512 + d], B[l*65536 + (i+64)*512 + d]);
  }
  // C4[((l*128 + j)*2 + dgw)*64 + i] = C[l][dgw*256 + k*64 + i][j] for k=0..3
  for (int idx = tid; idx < 4*128*2*64; idx += nth){
    int l = idx >> 14, rem = idx & 16383;
    int j = rem >> 7, dgw = (rem >> 6) & 1, i = rem & 63;
    const float* Cl = C + l*65536;
    C4[idx] = make_float4(Cl[(dgw*256 +   0 + i)*128 + j],
                          Cl[(dgw*256 +  64 + i)*128 + j],
                          Cl[(dgw*256 + 128 + i)*128 + j],
                          Cl[(dgw*256 + 192 + i)*128 + j]);
  }
}

// ---------------- temporal encode -> bitmasks (verified) ----------------
__global__ __launch_bounds__(256) void enc_k(
    const int* __restrict__ ids, const float* __restrict__ emb, uint* __restrict__ X0){
  int tid = threadIdx.x;
  int h = tid & 31, rloc = tid >> 5;
  int r = blockIdx.x * 8 + rloc;
  int id = ids[r];
  uint half = (uint)((rloc & 1) * 32);
  int kk[16];
  #pragma unroll
  for (int w = 0; w < 16; w++){
    float e    = emb[(size_t)id * DM + w*32 + h];
    float ex32 = (float)exp(-(double)e);     // correctly-rounded f32 exp(-x)
    float sg   = 1.0f / (1.0f + ex32);
    float p    = sg * 19.0f;
    int k = (int)floorf(p);
    if (k > TT-1) k = TT-1;
    kk[w] = k;
  }
  uint* Xr = X0 + (size_t)r * (TT*16);
  for (int t = 0; t < TT; t++){
    #pragma unroll
    for (int w = 0; w < 16; w++){
      uint bw = (uint)(__ballot(kk[w] == t) >> half);
      if (h == 0) Xr[t*16 + w] = bw;
    }
  }
}

// ---------------- kernel A: X@B.T (all t) then LIF1 recurrence -> H ----------------
// r13 structure (best measured): 256-thr block = 4 waves = 4 rows, (256,2),
// breg[16] L2 prefetch. NEW: selector as wave-uniform 64-bit select
// (s_cselect_b64 of packed (1,1)) feeding v_pk_fma_f32 via SGPR pair ->
// 1 VALU per (d,t) state-pair (was 2: cndmask + pk_fma). Bit-exact: each half
// multiplies by exactly 1.0/0.0, chain order unchanged.
__global__ __launch_bounds__(256, 2) void snn_a_k(
    int l, const uint* __restrict__ Xin, const float2* __restrict__ A2,
    const float2* __restrict__ B2, uint* __restrict__ H){
  __shared__ float2 As[128*64];    // 64 KB: As[j*64+i2] = (A[i2][j], A[i2+64][j])
  int tid  = threadIdx.x;
  int lane = tid & 63, wv = tid >> 6;
  size_t r = (size_t)blockIdx.x * 4 + wv;

  { // stage A layer slice (float4 coop loads)
    const float4* Ag = (const float4*)(A2 + l * 8192);
    float4* Asv = (float4*)As;
    #pragma unroll
    for (int p = 0; p < 16; p++) Asv[tid + p*256] = Ag[tid + p*256];
  }
  __syncthreads();

  const uint* Xr = Xin + r * (TT*16);
  f32x2 acc[TT];
  #pragma unroll
  for (int t = 0; t < TT; t++) acc[t] = (f32x2){0.f, 0.f};

  // ---- B-phase: acc[t] = (x[t] @ B.T)[i pair], d ascending (dw, g, u) ----
  const float2* Bl = B2 + l * 32768;
  for (int dw = 0; dw < 16; dw++){
    uint sw[TT];
    #pragma unroll
    for (int t = 0; t < TT; t++)
      sw[t] = __builtin_amdgcn_readfirstlane(Xr[t*16 + dw]);
    #pragma unroll
    for (int g = 0; g < 2; g++){
      f32x2 breg[16];                      // 16 loads in flight
      #pragma unroll
      for (int u = 0; u < 16; u++){
        float2 b = Bl[(dw*32 + g*16 + u) * 64 + lane];
        breg[u] = (f32x2){b.x, b.y};
      }
      #pragma unroll
      for (int u = 0; u < 16; u++){
        int db = g*16 + u;
        #pragma unroll
        for (int t = 0; t < TT; t++){
          ull sel = ((sw[t] >> db) & 1u) ? ONE2 : 0ull;     // s_cselect_b64
          acc[t] = __builtin_elementwise_fma(__builtin_bit_cast(f32x2, sel),
                                             breg[u], acc[t]);
        }
      }
    }
  }

  // ---- LIF1 recurrence over t (t unrolled for static acc; j-loops rolled @8) ----
  f32x2 v1 = {0.f, 0.f};
  ull m0 = 0, m1 = 0;      // h masks: states 0-63 / 64-127 (wave-uniform)
  #pragma unroll
  for (int t = 0; t < TT; t++){
    f32x2 t1 = {0.f, 0.f};
    #pragma unroll 8
    for (int j = 0; j < 64; j++){
      ull sel = ((m0 >> j) & 1ull) ? ONE2 : 0ull;
      float2 a = As[j*64 + lane];
      t1 = __builtin_elementwise_fma(__builtin_bit_cast(f32x2, sel),
                                     (f32x2){a.x, a.y}, t1);
    }
    #pragma unroll 8
    for (int j = 0; j < 64; j++){
      ull sel = ((m1 >> j) & 1ull) ? ONE2 : 0ull;
      float2 a = As[(64 + j)*64 + lane];
      t1 = __builtin_elementwise_fma(__builtin_bit_cast(f32x2, sel),
                                     (f32x2){a.x, a.y}, t1);
    }
    f32x2 su = t1 + acc[t];               // np: (h@A.T) + (x@B.T), one add per half
    v1 = v1 + (su - v1) * 0.5f;           // LIF, tau=2 (exact *0.5 per half)
    bool sa = (v1.x >= 1.0f), sb = (v1.y >= 1.0f);
    if (sa) v1.x = 0.0f;                  // hard reset
    if (sb) v1.y = 0.0f;
    m0 = __ballot(sa);
    m1 = __ballot(sb);
    if (lane == 0)
      *(uint4*)(H + (r*TT + t)*4) =
        make_uint4((uint)m0, (uint)(m0 >> 32), (uint)m1, (uint)(m1 >> 32));
  }
}

// ---------------- kernel B: H@C.T then LIF2 -> X' (C4 packed + pk selector) ----------------
// block = 2 rows x 2 half-d waves (1024 blocks). Lane owns d = dgw*256 + k*64 + lane,
// C columns packed in one float4; one shared sel feeds two pk_fma -> 2 VALU per
// (j,t) (was 4 fma + sel). Each acc half = own chain ascending j -> bit-exact.
__global__ __launch_bounds__(256, 4) void snn_b_k(
    int l, int last, const uint* __restrict__ Xin, const uint* __restrict__ Hg,
    const float4* __restrict__ C4, const float* __restrict__ Dfull,
    uint* __restrict__ Xout, ushort* __restrict__ tib){
  int tid = threadIdx.x;
  int lane = tid & 63, wv = tid >> 6;
  int rloc = wv >> 1, dgw = wv & 1;
  size_t r = (size_t)blockIdx.x * 2 + rloc;

  f32x2 acc01[TT], acc23[TT];
  #pragma unroll
  for (int t = 0; t < TT; t++){ acc01[t] = (f32x2){0.f,0.f}; acc23[t] = (f32x2){0.f,0.f}; }

  const float4* Cp = C4 + (((size_t)l*128)*2 + dgw)*64 + lane;   // per j: Cp[j*128]
  const uint*   Hr = Hg + r * (TT*4);
  for (int jw = 0; jw < 4; jw++){
    uint sw[TT];
    #pragma unroll
    for (int t = 0; t < TT; t++)
      sw[t] = __builtin_amdgcn_readfirstlane(Hr[t*4 + jw]);
    #pragma unroll 4
    for (int jb = 0; jb < 32; jb++){
      float4 cv = Cp[(size_t)(jw*32 + jb) * 128];
      f32x2 c01 = {cv.x, cv.y}, c23 = {cv.z, cv.w};
      #pragma unroll
      for (int t = 0; t < TT; t++){
        ull sel = ((sw[t] >> jb) & 1u) ? ONE2 : 0ull;
        f32x2 sf2 = __builtin_bit_cast(f32x2, sel);
        acc01[t] = __builtin_elementwise_fma(sf2, c01, acc01[t]);
        acc23[t] = __builtin_elementwise_fma(sf2, c23, acc23[t]);
      }
    }
  }

  // LIF2 over t (fully unrolled); k: 0=acc01.x 1=acc01.y 2=acc23.x 3=acc23.y
  float dv[4];
  #pragma unroll
  for (int k = 0; k < 4; k++) dv[k] = Dfull[l*DM + dgw*256 + k*64 + lane];
  float v2[4] = {0.f,0.f,0.f,0.f};
  int cnt[4] = {0,0,0,0};
  const uint* Xr = Xin + r * (TT*16) + dgw*8 + (lane >> 5);
  #pragma unroll
  for (int t = 0; t < TT; t++){
    float av[4] = { acc01[t].x, acc01[t].y, acc23[t].x, acc23[t].y };
    bool s[4];
    #pragma unroll
    for (int k = 0; k < 4; k++){
      uint xw = Xr[t*16 + k*2];
      float t4 = ((xw >> (lane & 31)) & 1u) ? dv[k] : 0.0f;  // x_t * D
      float ou = av[k] + t4;                  // np: (h@C.T) + x*D, one add
      v2[k] = v2[k] + (ou - v2[k]) * 0.5f;
      s[k] = (v2[k] >= 1.0f);
      if (s[k]) v2[k] = 0.0f;
    }
    if (!last){
      #pragma unroll
      for (int k = 0; k < 4; k++){
        ull bm = __ballot(s[k]);
        if (lane == 0){
          Xout[(r*TT + t)*16 + dgw*8 + k*2]     = (uint)bm;
          Xout[(r*TT + t)*16 + dgw*8 + k*2 + 1] = (uint)(bm >> 32);
        }
      }
    } else {
      #pragma unroll
      for (int k = 0; k < 4; k++) cnt[k] += s[k] ? 1 : 0;
    }
  }
  if (last){
    #pragma unroll
    for (int k = 0; k < 4; k++)
      tib[r*DM + dgw*256 + k*64 + lane] = f2bf((float)cnt[k] / 20.0f);
  }
}

// ---------------- final projection: bf16 MFMA, BM=256 tile + XCD panel swizzle ----------------
__global__ __launch_bounds__(512, 2) void gemm_mfma_k(
    const ushort* __restrict__ tib, const float* __restrict__ Wp,
    const float* __restrict__ bp, float* __restrict__ out){
  __shared__ ushort lA[256*64];    // 32 KB
  __shared__ ushort lB[128*64];    // 16 KB
  int bid = blockIdx.x;
  int L = (bid & 7) * 250 + (bid >> 3);    // bijective on [0,2000)
  int m0 = (L & 7) * 256;
  int n0 = (L >> 3) * 128;
  int tid = threadIdx.x;
  int lane = tid & 63, wv = tid >> 6;      // 8 waves
  int wm = wv >> 1, wn = wv & 1;

  f32x4 acc[4][4];
  #pragma unroll
  for (int i = 0; i < 4; i++)
    #pragma unroll
    for (int j = 0; j < 4; j++) acc[i][j] = (f32x4){0.f,0.f,0.f,0.f};

  for (int k0 = 0; k0 < 512; k0 += 64){
    __syncthreads();
    #pragma unroll
    for (int i = 0; i < 4; i++){     // A: 256x64, global_load_lds 16B, pre-swizzled src
      int slot = tid + i*512; int row = slot >> 3; int cb8 = (slot & 7) * 8;
      int sc = cb8 ^ ((row & 7) * 8);
      const ushort* gp = tib + (size_t)(m0 + row) * 512 + k0 + sc;
      __builtin_amdgcn_global_load_lds((const __attribute__((address_space(1))) void*)gp,
          (__attribute__((address_space(3))) void*)&lA[slot*8], 16, 0, 0);
    }
    #pragma unroll
    for (int i = 0; i < 2; i++){     // B: 128x64, reg-stage f32 -> bf16, swizzled dest
      int slot = tid + i*512; int row = slot >> 3; int cb8 = (slot & 7) * 8;
      int sc = cb8 ^ ((row & 7) * 8);
      const float* gp = Wp + (size_t)(n0 + row) * 512 + k0 + sc;
      float4 u = *(const float4*)gp;
      float4 v = *(const float4*)(gp + 4);
      us8 pk;
      pk[0]=f2bf(u.x); pk[1]=f2bf(u.y); pk[2]=f2bf(u.z); pk[3]=f2bf(u.w);
      pk[4]=f2bf(v.x); pk[5]=f2bf(v.y); pk[6]=f2bf(v.z); pk[7]=f2bf(v.w);
      *(us8*)&lB[slot*8] = pk;
    }
    __syncthreads();
    #pragma unroll
    for (int kk = 0; kk < 2; kk++){
      bf16x8 af[4], bf_[4];
      int c = kk*32 + (lane >> 4) * 8;
      #pragma unroll
      for (int mi = 0; mi < 4; mi++){
        int row = wm*64 + mi*16 + (lane & 15);
        af[mi] = *(const bf16x8*)&lA[row*64 + (c ^ ((row & 7) * 8))];
      }
      #pragma unroll
      for (int ni = 0; ni < 4; ni++){
        int row = wn*64 + ni*16 + (lane & 15);
        bf_[ni] = *(const bf16x8*)&lB[row*64 + (c ^ ((row & 7) * 8))];
      }
      #pragma unroll
      for (int mi = 0; mi < 4; mi++)
        #pragma unroll
        for (int ni = 0; ni < 4; ni++)
          acc[mi][ni] = __builtin_amdgcn_mfma_f32_16x16x32_bf16(af[mi], bf_[ni], acc[mi][ni], 0, 0, 0);
    }
  }

  #pragma unroll
  for (int ni = 0; ni < 4; ni++){
    int col = n0 + wn*64 + ni*16 + (lane & 15);
    float bb = bp[col];
    #pragma unroll
    for (int mi = 0; mi < 4; mi++){
      int rbase_ = m0 + wm*64 + mi*16 + (lane >> 4) * 4;
      #pragma unroll
      for (int rr = 0; rr < 4; rr++)
        out[(size_t)(rbase_ + rr) * NV + col] = acc[mi][ni][rr] + bb;
    }
  }
}

extern "C" void kernel_launch(void* const* d_in, const int* in_sizes, int n_in,
                              void* d_out, int out_size, void* d_ws, size_t ws_size,
                              hipStream_t stream) {
  const int*   ids = (const int*)  d_in[0];
  const float* emb = (const float*)d_in[1];
  const float* A   = (const float*)d_in[2];
  const float* B   = (const float*)d_in[3];
  const float* C   = (const float*)d_in[4];
  const float* D   = (const float*)d_in[5];
  const float* Wp  = (const float*)d_in[6];
  const float* bp  = (const float*)d_in[7];
  float* out = (float*)d_out;
  char* ws = (char*)d_ws;
  float2* A2  = (float2*)(ws + OFF_A2);
  float2* B2  = (float2*)(ws + OFF_B2);
  uint*   X0  = (uint*)  (ws + OFF_X0);
  uint*   X1  = (uint*)  (ws + OFF_X1);
  uint*   H   = (uint*)  (ws + OFF_H);
  ushort* tib = (ushort*)(ws + OFF_TIB);
  float4* C4  = (float4*)((char*)d_out + C4_OFF_OUT);  // scratch, gemm overwrites last

  bt_transpose_k<<<dim3(512), dim3(256), 0, stream>>>(A, B, C, A2, B2, C4);
  enc_k         <<<dim3(256), dim3(256), 0, stream>>>(ids, emb, X0);
  for (int l = 0; l < NL; l++){
    uint* Xin  = (l & 1) ? X1 : X0;
    uint* Xout = (l & 1) ? X0 : X1;
    snn_a_k<<<dim3(512),  dim3(256), 0, stream>>>(l, Xin, A2, B2, H);
    snn_b_k<<<dim3(1024), dim3(256), 0, stream>>>(l, (l == NL-1) ? 1 : 0, Xin, H, C4, D, Xout, tib);
  }
  gemm_mfma_k<<<dim3(2000), dim3(512), 0, stream>>>(tib, Wp, bp, out);
}

// Round 18
// 1055.862 us; speedup vs baseline: 1.2607x; 1.0618x over previous
//
#include <hip/hip_runtime.h>
#include <math.h>

typedef unsigned int uint;
typedef unsigned long long ull;
typedef unsigned short ushort;

#define DM   512
#define DS   128
#define TT   20
#define NL   4
#define NV   32000
#define NROW 2048

// packed (1.0f,1.0f) for the wave-uniform pk_fma selector (SGPR pair)
#define ONE2 0x3F8000003F800000ull

// ws layout (~10.4 MB base)
#define OFF_A2  0u          // 4*128*64 float2  A2[l][j][i2] = (A[i2][j], A[i2+64][j])
#define OFF_B4  262144u     // 4*256*64 float4  B4[l][d2][i] = (B[i][2d2],B[i+64][2d2],B[i][2d2+1],B[i+64][2d2+1])
#define OFF_X0  2359296u    // 2048*20*16 u32   spike masks ping (bit d&31 of word d>>5)
#define OFF_X1  4980736u    // 2621440          spike masks pong
#define OFF_H   7602176u    // 2048*20*4 u32    h masks
#define OFF_TIB 8257536u    // 2048*512 bf16    time-integrated
// optional (only if ws_size permits): pre-converted Wp in bf16
#define OFF_WPB 16777216u   // 32000*512 bf16 = 32,768,000 B
#define WPB_BYTES 32768000u

// d_out scratch (gemm fully overwrites d_out last):
//   C4: [l][j][dgw][lane] float4 = 2,097,152 B at offset 32 MB
#define C4_OFF_OUT 33554432u

typedef float f32x2 __attribute__((ext_vector_type(2)));
typedef float f32x4 __attribute__((ext_vector_type(4)));
typedef __bf16 bf16x8 __attribute__((ext_vector_type(8)));
typedef ushort us8 __attribute__((ext_vector_type(8)));

__device__ __forceinline__ ushort f2bf(float f){   // RNE f32->bf16
  uint x = __float_as_uint(f);
  uint r = x + 0x7fffu + ((x >> 16) & 1u);
  return (ushort)(r >> 16);
}

// ---------------- weight prep: paired A + quad B layouts + packed C4 ----------------
__global__ __launch_bounds__(256) void bt_transpose_k(
    const float* __restrict__ A, const float* __restrict__ B, const float* __restrict__ C,
    float2* __restrict__ A2, float4* __restrict__ B4, float4* __restrict__ C4){
  int tid = blockIdx.x * 256 + threadIdx.x;
  int nth = gridDim.x * 256;
  for (int idx = tid; idx < 4*128*64; idx += nth){
    int l = idx >> 13, j = (idx >> 6) & 127, i = idx & 63;
    A2[idx] = make_float2(A[l*16384 + i*128 + j], A[l*16384 + (i+64)*128 + j]);
  }
  // B4[l][d2][i]: both states (i, i+64) for d = 2*d2 and 2*d2+1 in one 16B word
  for (int idx = tid; idx < 4*256*64; idx += nth){
    int l = idx >> 14, d2 = (idx >> 6) & 255, i = idx & 63;
    const float* Bl = B + l*65536;
    B4[idx] = make_float4(Bl[i*512 + 2*d2],     Bl[(i+64)*512 + 2*d2],
                          Bl[i*512 + 2*d2 + 1], Bl[(i+64)*512 + 2*d2 + 1]);
  }
  // C4[((l*128 + j)*2 + dgw)*64 + i] = C[l][dgw*256 + k*64 + i][j] for k=0..3
  for (int idx = tid; idx < 4*128*2*64; idx += nth){
    int l = idx >> 14, rem = idx & 16383;
    int j = rem >> 7, dgw = (rem >> 6) & 1, i = rem & 63;
    const float* Cl = C + l*65536;
    C4[idx] = make_float4(Cl[(dgw*256 +   0 + i)*128 + j],
                          Cl[(dgw*256 +  64 + i)*128 + j],
                          Cl[(dgw*256 + 128 + i)*128 + j],
                          Cl[(dgw*256 + 192 + i)*128 + j]);
  }
}

// ---------------- optional: Wp f32 -> bf16 once (bit-identical RNE) ----------------
__global__ __launch_bounds__(256) void wpb_k(
    const float* __restrict__ Wp, ushort* __restrict__ Wpb){
  size_t idx = ((size_t)blockIdx.x * 256 + threadIdx.x) * 8;
  float4 u = *(const float4*)(Wp + idx);
  float4 v = *(const float4*)(Wp + idx + 4);
  us8 pk;
  pk[0]=f2bf(u.x); pk[1]=f2bf(u.y); pk[2]=f2bf(u.z); pk[3]=f2bf(u.w);
  pk[4]=f2bf(v.x); pk[5]=f2bf(v.y); pk[6]=f2bf(v.z); pk[7]=f2bf(v.w);
  *(us8*)(Wpb + idx) = pk;
}

// ---------------- temporal encode -> bitmasks (verified) ----------------
__global__ __launch_bounds__(256) void enc_k(
    const int* __restrict__ ids, const float* __restrict__ emb, uint* __restrict__ X0){
  int tid = threadIdx.x;
  int h = tid & 31, rloc = tid >> 5;
  int r = blockIdx.x * 8 + rloc;
  int id = ids[r];
  uint half = (uint)((rloc & 1) * 32);
  int kk[16];
  #pragma unroll
  for (int w = 0; w < 16; w++){
    float e    = emb[(size_t)id * DM + w*32 + h];
    float ex32 = (float)exp(-(double)e);     // correctly-rounded f32 exp(-x)
    float sg   = 1.0f / (1.0f + ex32);
    float p    = sg * 19.0f;
    int k = (int)floorf(p);
    if (k > TT-1) k = TT-1;
    kk[w] = k;
  }
  uint* Xr = X0 + (size_t)r * (TT*16);
  for (int t = 0; t < TT; t++){
    #pragma unroll
    for (int w = 0; w < 16; w++){
      uint bw = (uint)(__ballot(kk[w] == t) >> half);
      if (h == 0) Xr[t*16 + w] = bw;
    }
  }
}

// ---------------- kernel A: X@B.T (all t) then LIF1 recurrence -> H ----------------
// r17 structure + (a) mask double-buffer (next dw's words loaded before consuming
// current -> L2 latency hidden), (b) B4 16B loads (half the VMEM insts).
// Selector = s_cselect_b64 of packed (1,1) feeding v_pk_fma_f32 via SGPR pair.
// Chain per (t,i): single f32 acc, d ascending -> bit-exact.
__global__ __launch_bounds__(256, 2) void snn_a_k(
    int l, const uint* __restrict__ Xin, const float2* __restrict__ A2,
    const float4* __restrict__ B4, uint* __restrict__ H){
  __shared__ float2 As[128*64];    // 64 KB: As[j*64+i2] = (A[i2][j], A[i2+64][j])
  int tid  = threadIdx.x;
  int lane = tid & 63, wv = tid >> 6;
  size_t r = (size_t)blockIdx.x * 4 + wv;

  { // stage A layer slice (float4 coop loads)
    const float4* Ag = (const float4*)(A2 + l * 8192);
    float4* Asv = (float4*)As;
    #pragma unroll
    for (int p = 0; p < 16; p++) Asv[tid + p*256] = Ag[tid + p*256];
  }
  __syncthreads();

  const uint* Xr = Xin + r * (TT*16);
  f32x2 acc[TT];
  #pragma unroll
  for (int t = 0; t < TT; t++) acc[t] = (f32x2){0.f, 0.f};

  // ---- B-phase: acc[t] = (x[t] @ B.T)[i pair], d ascending (dw, g, u, lo/hi) ----
  const float4* Bl = B4 + l * 16384 + lane;
  uint swv[TT];
  #pragma unroll
  for (int t = 0; t < TT; t++) swv[t] = Xr[t*16];      // dw=0 words
  for (int dw = 0; dw < 16; dw++){
    uint sw[TT];
    #pragma unroll
    for (int t = 0; t < TT; t++) sw[t] = __builtin_amdgcn_readfirstlane(swv[t]);
    if (dw < 15){                                      // prefetch next dw's words
      #pragma unroll
      for (int t = 0; t < TT; t++) swv[t] = Xr[t*16 + dw + 1];
    }
    #pragma unroll
    for (int g = 0; g < 2; g++){
      f32x4 breg[8];                                   // 8 x 16B loads in flight = 16 d
      #pragma unroll
      for (int u = 0; u < 8; u++){
        float4 b = Bl[(size_t)(dw*16 + g*8 + u) * 64];
        breg[u] = (f32x4){b.x, b.y, b.z, b.w};
      }
      #pragma unroll
      for (int u = 0; u < 8; u++){
        int db = g*16 + 2*u;
        #pragma unroll
        for (int t = 0; t < TT; t++){
          ull s0 = ((sw[t] >> db) & 1u) ? ONE2 : 0ull;         // d = even
          acc[t] = __builtin_elementwise_fma(__builtin_bit_cast(f32x2, s0),
                     (f32x2){breg[u].x, breg[u].y}, acc[t]);
          ull s1 = ((sw[t] >> (db+1)) & 1u) ? ONE2 : 0ull;     // d = odd
          acc[t] = __builtin_elementwise_fma(__builtin_bit_cast(f32x2, s1),
                     (f32x2){breg[u].z, breg[u].w}, acc[t]);
        }
      }
    }
  }

  // ---- LIF1 recurrence over t (t unrolled for static acc; j-loops rolled @8) ----
  f32x2 v1 = {0.f, 0.f};
  ull m0 = 0, m1 = 0;      // h masks: states 0-63 / 64-127 (wave-uniform)
  #pragma unroll
  for (int t = 0; t < TT; t++){
    f32x2 t1 = {0.f, 0.f};
    #pragma unroll 8
    for (int j = 0; j < 64; j++){
      ull sel = ((m0 >> j) & 1ull) ? ONE2 : 0ull;
      float2 a = As[j*64 + lane];
      t1 = __builtin_elementwise_fma(__builtin_bit_cast(f32x2, sel),
                                     (f32x2){a.x, a.y}, t1);
    }
    #pragma unroll 8
    for (int j = 0; j < 64; j++){
      ull sel = ((m1 >> j) & 1ull) ? ONE2 : 0ull;
      float2 a = As[(64 + j)*64 + lane];
      t1 = __builtin_elementwise_fma(__builtin_bit_cast(f32x2, sel),
                                     (f32x2){a.x, a.y}, t1);
    }
    f32x2 su = t1 + acc[t];               // np: (h@A.T) + (x@B.T), one add per half
    v1 = v1 + (su - v1) * 0.5f;           // LIF, tau=2 (exact *0.5 per half)
    bool sa = (v1.x >= 1.0f), sb = (v1.y >= 1.0f);
    if (sa) v1.x = 0.0f;                  // hard reset
    if (sb) v1.y = 0.0f;
    m0 = __ballot(sa);
    m1 = __ballot(sb);
    if (lane == 0)
      *(uint4*)(H + (r*TT + t)*4) =
        make_uint4((uint)m0, (uint)(m0 >> 32), (uint)m1, (uint)(m1 >> 32));
  }
}

// ---------------- kernel B: H@C.T then LIF2 -> X' (r17-verbatim) ----------------
__global__ __launch_bounds__(256, 4) void snn_b_k(
    int l, int last, const uint* __restrict__ Xin, const uint* __restrict__ Hg,
    const float4* __restrict__ C4, const float* __restrict__ Dfull,
    uint* __restrict__ Xout, ushort* __restrict__ tib){
  int tid = threadIdx.x;
  int lane = tid & 63, wv = tid >> 6;
  int rloc = wv >> 1, dgw = wv & 1;
  size_t r = (size_t)blockIdx.x * 2 + rloc;

  f32x2 acc01[TT], acc23[TT];
  #pragma unroll
  for (int t = 0; t < TT; t++){ acc01[t] = (f32x2){0.f,0.f}; acc23[t] = (f32x2){0.f,0.f}; }

  const float4* Cp = C4 + (((size_t)l*128)*2 + dgw)*64 + lane;   // per j: Cp[j*128]
  const uint*   Hr = Hg + r * (TT*4);
  for (int jw = 0; jw < 4; jw++){
    uint sw[TT];
    #pragma unroll
    for (int t = 0; t < TT; t++)
      sw[t] = __builtin_amdgcn_readfirstlane(Hr[t*4 + jw]);
    #pragma unroll 4
    for (int jb = 0; jb < 32; jb++){
      float4 cv = Cp[(size_t)(jw*32 + jb) * 128];
      f32x2 c01 = {cv.x, cv.y}, c23 = {cv.z, cv.w};
      #pragma unroll
      for (int t = 0; t < TT; t++){
        ull sel = ((sw[t] >> jb) & 1u) ? ONE2 : 0ull;
        f32x2 sf2 = __builtin_bit_cast(f32x2, sel);
        acc01[t] = __builtin_elementwise_fma(sf2, c01, acc01[t]);
        acc23[t] = __builtin_elementwise_fma(sf2, c23, acc23[t]);
      }
    }
  }

  // LIF2 over t (fully unrolled); k: 0=acc01.x 1=acc01.y 2=acc23.x 3=acc23.y
  float dv[4];
  #pragma unroll
  for (int k = 0; k < 4; k++) dv[k] = Dfull[l*DM + dgw*256 + k*64 + lane];
  float v2[4] = {0.f,0.f,0.f,0.f};
  int cnt[4] = {0,0,0,0};
  const uint* Xr = Xin + r * (TT*16) + dgw*8 + (lane >> 5);
  #pragma unroll
  for (int t = 0; t < TT; t++){
    float av[4] = { acc01[t].x, acc01[t].y, acc23[t].x, acc23[t].y };
    bool s[4];
    #pragma unroll
    for (int k = 0; k < 4; k++){
      uint xw = Xr[t*16 + k*2];
      float t4 = ((xw >> (lane & 31)) & 1u) ? dv[k] : 0.0f;  // x_t * D
      float ou = av[k] + t4;                  // np: (h@C.T) + x*D, one add
      v2[k] = v2[k] + (ou - v2[k]) * 0.5f;
      s[k] = (v2[k] >= 1.0f);
      if (s[k]) v2[k] = 0.0f;
    }
    if (!last){
      #pragma unroll
      for (int k = 0; k < 4; k++){
        ull bm = __ballot(s[k]);
        if (lane == 0){
          Xout[(r*TT + t)*16 + dgw*8 + k*2]     = (uint)bm;
          Xout[(r*TT + t)*16 + dgw*8 + k*2 + 1] = (uint)(bm >> 32);
        }
      }
    } else {
      #pragma unroll
      for (int k = 0; k < 4; k++) cnt[k] += s[k] ? 1 : 0;
    }
  }
  if (last){
    #pragma unroll
    for (int k = 0; k < 4; k++)
      tib[r*DM + dgw*256 + k*64 + lane] = f2bf((float)cnt[k] / 20.0f);
  }
}

// ---------------- final projection (pre-converted Wpb): both tiles via gload_lds ----------------
__global__ __launch_bounds__(512, 2) void gemm_pre_k(
    const ushort* __restrict__ tib, const ushort* __restrict__ Wpb,
    const float* __restrict__ bp, float* __restrict__ out){
  __shared__ ushort lA[256*64];    // 32 KB
  __shared__ ushort lB[128*64];    // 16 KB
  int bid = blockIdx.x;
  int L = (bid & 7) * 250 + (bid >> 3);    // bijective on [0,2000)
  int m0 = (L & 7) * 256;
  int n0 = (L >> 3) * 128;
  int tid = threadIdx.x;
  int lane = tid & 63, wv = tid >> 6;      // 8 waves
  int wm = wv >> 1, wn = wv & 1;

  f32x4 acc[4][4];
  #pragma unroll
  for (int i = 0; i < 4; i++)
    #pragma unroll
    for (int j = 0; j < 4; j++) acc[i][j] = (f32x4){0.f,0.f,0.f,0.f};

  for (int k0 = 0; k0 < 512; k0 += 64){
    __syncthreads();
    #pragma unroll
    for (int i = 0; i < 4; i++){     // A: 256x64 bf16 via gload_lds, pre-swizzled src
      int slot = tid + i*512; int row = slot >> 3; int cb8 = (slot & 7) * 8;
      int sc = cb8 ^ ((row & 7) * 8);
      const ushort* gp = tib + (size_t)(m0 + row) * 512 + k0 + sc;
      __builtin_amdgcn_global_load_lds((const __attribute__((address_space(1))) void*)gp,
          (__attribute__((address_space(3))) void*)&lA[slot*8], 16, 0, 0);
    }
    #pragma unroll
    for (int i = 0; i < 2; i++){     // B: 128x64 bf16 via gload_lds (no conversion!)
      int slot = tid + i*512; int row = slot >> 3; int cb8 = (slot & 7) * 8;
      int sc = cb8 ^ ((row & 7) * 8);
      const ushort* gp = Wpb + (size_t)(n0 + row) * 512 + k0 + sc;
      __builtin_amdgcn_global_load_lds((const __attribute__((address_space(1))) void*)gp,
          (__attribute__((address_space(3))) void*)&lB[slot*8], 16, 0, 0);
    }
    __syncthreads();
    #pragma unroll
    for (int kk = 0; kk < 2; kk++){
      bf16x8 af[4], bf_[4];
      int c = kk*32 + (lane >> 4) * 8;
      #pragma unroll
      for (int mi = 0; mi < 4; mi++){
        int row = wm*64 + mi*16 + (lane & 15);
        af[mi] = *(const bf16x8*)&lA[row*64 + (c ^ ((row & 7) * 8))];
      }
      #pragma unroll
      for (int ni = 0; ni < 4; ni++){
        int row = wn*64 + ni*16 + (lane & 15);
        bf_[ni] = *(const bf16x8*)&lB[row*64 + (c ^ ((row & 7) * 8))];
      }
      #pragma unroll
      for (int mi = 0; mi < 4; mi++)
        #pragma unroll
        for (int ni = 0; ni < 4; ni++)
          acc[mi][ni] = __builtin_amdgcn_mfma_f32_16x16x32_bf16(af[mi], bf_[ni], acc[mi][ni], 0, 0, 0);
    }
  }

  #pragma unroll
  for (int ni = 0; ni < 4; ni++){
    int col = n0 + wn*64 + ni*16 + (lane & 15);
    float bb = bp[col];
    #pragma unroll
    for (int mi = 0; mi < 4; mi++){
      int rbase_ = m0 + wm*64 + mi*16 + (lane >> 4) * 4;
      #pragma unroll
      for (int rr = 0; rr < 4; rr++)
        out[(size_t)(rbase_ + rr) * NV + col] = acc[mi][ni][rr] + bb;
    }
  }
}

// ---------------- fallback gemm (r17-verbatim, in-loop conversion) ----------------
__global__ __launch_bounds__(512, 2) void gemm_mfma_k(
    const ushort* __restrict__ tib, const float* __restrict__ Wp,
    const float* __restrict__ bp, float* __restrict__ out){
  __shared__ ushort lA[256*64];
  __shared__ ushort lB[128*64];
  int bid = blockIdx.x;
  int L = (bid & 7) * 250 + (bid >> 3);
  int m0 = (L & 7) * 256;
  int n0 = (L >> 3) * 128;
  int tid = threadIdx.x;
  int lane = tid & 63, wv = tid >> 6;
  int wm = wv >> 1, wn = wv & 1;

  f32x4 acc[4][4];
  #pragma unroll
  for (int i = 0; i < 4; i++)
    #pragma unroll
    for (int j = 0; j < 4; j++) acc[i][j] = (f32x4){0.f,0.f,0.f,0.f};

  for (int k0 = 0; k0 < 512; k0 += 64){
    __syncthreads();
    #pragma unroll
    for (int i = 0; i < 4; i++){
      int slot = tid + i*512; int row = slot >> 3; int cb8 = (slot & 7) * 8;
      int sc = cb8 ^ ((row & 7) * 8);
      const ushort* gp = tib + (size_t)(m0 + row) * 512 + k0 + sc;
      __builtin_amdgcn_global_load_lds((const __attribute__((address_space(1))) void*)gp,
          (__attribute__((address_space(3))) void*)&lA[slot*8], 16, 0, 0);
    }
    #pragma unroll
    for (int i = 0; i < 2; i++){
      int slot = tid + i*512; int row = slot >> 3; int cb8 = (slot & 7) * 8;
      int sc = cb8 ^ ((row & 7) * 8);
      const float* gp = Wp + (size_t)(n0 + row) * 512 + k0 + sc;
      float4 u = *(const float4*)gp;
      float4 v = *(const float4*)(gp + 4);
      us8 pk;
      pk[0]=f2bf(u.x); pk[1]=f2bf(u.y); pk[2]=f2bf(u.z); pk[3]=f2bf(u.w);
      pk[4]=f2bf(v.x); pk[5]=f2bf(v.y); pk[6]=f2bf(v.z); pk[7]=f2bf(v.w);
      *(us8*)&lB[slot*8] = pk;
    }
    __syncthreads();
    #pragma unroll
    for (int kk = 0; kk < 2; kk++){
      bf16x8 af[4], bf_[4];
      int c = kk*32 + (lane >> 4) * 8;
      #pragma unroll
      for (int mi = 0; mi < 4; mi++){
        int row = wm*64 + mi*16 + (lane & 15);
        af[mi] = *(const bf16x8*)&lA[row*64 + (c ^ ((row & 7) * 8))];
      }
      #pragma unroll
      for (int ni = 0; ni < 4; ni++){
        int row = wn*64 + ni*16 + (lane & 15);
        bf_[ni] = *(const bf16x8*)&lB[row*64 + (c ^ ((row & 7) * 8))];
      }
      #pragma unroll
      for (int mi = 0; mi < 4; mi++)
        #pragma unroll
        for (int ni = 0; ni < 4; ni++)
          acc[mi][ni] = __builtin_amdgcn_mfma_f32_16x16x32_bf16(af[mi], bf_[ni], acc[mi][ni], 0, 0, 0);
    }
  }

  #pragma unroll
  for (int ni = 0; ni < 4; ni++){
    int col = n0 + wn*64 + ni*16 + (lane & 15);
    float bb = bp[col];
    #pragma unroll
    for (int mi = 0; mi < 4; mi++){
      int rbase_ = m0 + wm*64 + mi*16 + (lane >> 4) * 4;
      #pragma unroll
      for (int rr = 0; rr < 4; rr++)
        out[(size_t)(rbase_ + rr) * NV + col] = acc[mi][ni][rr] + bb;
    }
  }
}

extern "C" void kernel_launch(void* const* d_in, const int* in_sizes, int n_in,
                              void* d_out, int out_size, void* d_ws, size_t ws_size,
                              hipStream_t stream) {
  const int*   ids = (const int*)  d_in[0];
  const float* emb = (const float*)d_in[1];
  const float* A   = (const float*)d_in[2];
  const float* B   = (const float*)d_in[3];
  const float* C   = (const float*)d_in[4];
  const float* D   = (const float*)d_in[5];
  const float* Wp  = (const float*)d_in[6];
  const float* bp  = (const float*)d_in[7];
  float* out = (float*)d_out;
  char* ws = (char*)d_ws;
  float2* A2  = (float2*)(ws + OFF_A2);
  float4* B4  = (float4*)(ws + OFF_B4);
  uint*   X0  = (uint*)  (ws + OFF_X0);
  uint*   X1  = (uint*)  (ws + OFF_X1);
  uint*   H   = (uint*)  (ws + OFF_H);
  ushort* tib = (ushort*)(ws + OFF_TIB);
  float4* C4  = (float4*)((char*)d_out + C4_OFF_OUT);  // scratch, gemm overwrites last

  int pre = (ws_size >= (size_t)OFF_WPB + WPB_BYTES) ? 1 : 0;  // fixed per problem
  ushort* Wpb = (ushort*)(ws + OFF_WPB);

  bt_transpose_k<<<dim3(512), dim3(256), 0, stream>>>(A, B, C, A2, B4, C4);
  if (pre) wpb_k<<<dim3(8000), dim3(256), 0, stream>>>(Wp, Wpb);
  enc_k         <<<dim3(256), dim3(256), 0, stream>>>(ids, emb, X0);
  for (int l = 0; l < NL; l++){
    uint* Xin  = (l & 1) ? X1 : X0;
    uint* Xout = (l & 1) ? X0 : X1;
    snn_a_k<<<dim3(512),  dim3(256), 0, stream>>>(l, Xin, A2, B4, H);
    snn_b_k<<<dim3(1024), dim3(256), 0, stream>>>(l, (l == NL-1) ? 1 : 0, Xin, H, C4, D, Xout, tib);
  }
  if (pre) gemm_pre_k <<<dim3(2000), dim3(512), 0, stream>>>(tib, Wpb, bp, out);
  else     gemm_mfma_k<<<dim3(2000), dim3(512), 0, stream>>>(tib, Wp,  bp, out);
}